// Round 1
// baseline (3633.213 us; speedup 1.0000x reference)
//
#include <hip/hip_runtime.h>
#include <math.h>

#define BB 4
#define CC 512
#define NN 4096

// ---------------- Kernel 1: projections Bm,Cm,Dm = W{b,c,d} @ x ----------------
// O[o][n] = sum_c W[o][c] * X[c][n]; one 64x64 tile per block, K chunked by 32.
__global__ __launch_bounds__(256) void proj_gemm(
    const float* __restrict__ x,
    const float* __restrict__ Wb,
    const float* __restrict__ Wc,
    const float* __restrict__ Wd,
    float* __restrict__ ws)
{
    const int bz = blockIdx.z;
    const int b = bz / 3;
    const int wsel = bz % 3;
    const float* __restrict__ W = (wsel == 0) ? Wb : (wsel == 1) ? Wc : Wd;
    const size_t plane = (size_t)CC * NN;
    float* __restrict__ O = ws + (size_t)wsel * BB * plane + (size_t)b * plane;
    const float* __restrict__ X = x + (size_t)b * plane;

    const int o0 = blockIdx.y * 64;
    const int n0 = blockIdx.x * 64;

    __shared__ float Ws[64][33];   // [o][k], +1 pad
    __shared__ float Xs[32][68];   // [k][n], pad keeps float4 alignment (68*4B % 16 == 0)

    const int t = threadIdx.x;
    const int to = t >> 4;
    const int tn = t & 15;

    float acc[4][4] = {};

    for (int kc = 0; kc < CC; kc += 32) {
        __syncthreads();
        #pragma unroll
        for (int q = 0; q < 2; ++q) {
            int fi = t + (q << 8);
            int r = fi >> 3;
            int c4 = (fi & 7) << 2;
            float4 v = *(const float4*)(W + (size_t)(o0 + r) * CC + (kc + c4));
            Ws[r][c4 + 0] = v.x; Ws[r][c4 + 1] = v.y; Ws[r][c4 + 2] = v.z; Ws[r][c4 + 3] = v.w;
        }
        #pragma unroll
        for (int q = 0; q < 2; ++q) {
            int fi = t + (q << 8);
            int r = fi >> 4;
            int c4 = (fi & 15) << 2;
            *(float4*)&Xs[r][c4] = *(const float4*)(X + (size_t)(kc + r) * NN + (n0 + c4));
        }
        __syncthreads();
        #pragma unroll
        for (int k = 0; k < 32; ++k) {
            float4 bv = *(float4*)&Xs[k][tn << 2];
            #pragma unroll
            for (int i = 0; i < 4; ++i) {
                float a = Ws[(to << 2) + i][k];
                acc[i][0] += a * bv.x;
                acc[i][1] += a * bv.y;
                acc[i][2] += a * bv.z;
                acc[i][3] += a * bv.w;
            }
        }
    }
    #pragma unroll
    for (int i = 0; i < 4; ++i) {
        float4 v = make_float4(acc[i][0], acc[i][1], acc[i][2], acc[i][3]);
        *(float4*)(O + (size_t)(o0 + (to << 2) + i) * NN + (n0 + (tn << 2))) = v;
    }
}

// ---------------- Kernel 2: flash-style attention + epilogue ----------------
// Per block: batch b, 64 query rows (n-tile). Online softmax over m in tiles of 64.
// L[n][m] = sum_c Bm[c][n]*Cm[c][m];  acc[n][c] += p[n][m]*Dm[c][m];  out = g*acc/l + x.
__global__ __launch_bounds__(512) void attn_kernel(
    const float* __restrict__ x,
    const float* __restrict__ gamma_p,
    const float* __restrict__ ws,
    float* __restrict__ out)
{
    const int b = blockIdx.y;
    const int n0 = blockIdx.x * 64;

    const size_t plane = (size_t)CC * NN;
    const float* __restrict__ Bm = ws + (size_t)b * plane;
    const float* __restrict__ Cm = ws + (size_t)BB * plane + (size_t)b * plane;
    const float* __restrict__ Dm = ws + (size_t)(2 * BB) * plane + (size_t)b * plane;

    __shared__ float smA[64][68];   // phase1: Bt [k][n]; after softmax: p tile [n][m]
    __shared__ float smD[64][132];  // phase1: Cs [k][m] (aliased); phase2: Ds [m][c]; epilogue: transpose buf
    __shared__ float mx_s[64];
    __shared__ float l_s[64];
    __shared__ float scale_s[64];

    float (* const Cs)[68] = reinterpret_cast<float(*)[68]>(&smD[0][0]);

    const int t = threadIdx.x;

    if (t < 64) { mx_s[t] = -INFINITY; l_s[t] = 0.0f; }

    // phase-1 mapping: 16 lanes (mq) x 32 row-pairs (ng)
    const int mq = t & 15;
    const int ng = t >> 4;
    const int n2 = ng << 1;
    const int mq4 = mq << 2;

    // phase-2 mapping: 32 c-float4 (ci) x 16 row-groups (ng2); rows ng2+16k
    const int ci = t & 31;
    const int ci4 = ci << 2;
    const int ng2 = t >> 5;

    float acc[4][4][4] = {};   // [q(128c chunk)][k4(row)][j(c)]

    #pragma unroll 1
    for (int m0 = 0; m0 < NN; m0 += 64) {
        // ---------- phase 1: logits ----------
        float L[2][4] = {};
        #pragma unroll 1
        for (int kc = 0; kc < CC; kc += 64) {
            __syncthreads();   // smA (p of prev tile) / smD consumed
            #pragma unroll
            for (int q = 0; q < 2; ++q) {
                int fi = t + (q << 9);
                int kk = fi >> 4;
                int n4 = (fi & 15) << 2;
                *(float4*)&smA[kk][n4] = *(const float4*)(Bm + (size_t)(kc + kk) * NN + (n0 + n4));
            }
            #pragma unroll
            for (int q = 0; q < 2; ++q) {
                int fi = t + (q << 9);
                int kk = fi >> 4;
                int m4 = (fi & 15) << 2;
                *(float4*)&Cs[kk][m4] = *(const float4*)(Cm + (size_t)(kc + kk) * NN + (m0 + m4));
            }
            __syncthreads();
            #pragma unroll
            for (int k = 0; k < 64; ++k) {
                float a0 = smA[k][n2];
                float a1 = smA[k][n2 + 1];
                float4 bv = *(float4*)&Cs[k][mq4];
                L[0][0] += a0 * bv.x; L[0][1] += a0 * bv.y; L[0][2] += a0 * bv.z; L[0][3] += a0 * bv.w;
                L[1][0] += a1 * bv.x; L[1][1] += a1 * bv.y; L[1][2] += a1 * bv.z; L[1][3] += a1 * bv.w;
            }
        }
        __syncthreads();   // done reading smA/smD as Bt/Cs
        // ---------- online softmax (rows n2, n2+1 live in one 16-lane group) ----------
        float ps[2][4];
        #pragma unroll
        for (int r = 0; r < 2; ++r) {
            const int n = n2 + r;
            float tm = fmaxf(fmaxf(L[r][0], L[r][1]), fmaxf(L[r][2], L[r][3]));
            #pragma unroll
            for (int off = 1; off < 16; off <<= 1)
                tm = fmaxf(tm, __shfl_xor(tm, off));
            float old = mx_s[n];
            float nm = fmaxf(old, tm);
            float p0 = __expf(L[r][0] - nm);
            float p1 = __expf(L[r][1] - nm);
            float p2 = __expf(L[r][2] - nm);
            float p3 = __expf(L[r][3] - nm);
            float rs = (p0 + p1) + (p2 + p3);
            #pragma unroll
            for (int off = 1; off < 16; off <<= 1)
                rs += __shfl_xor(rs, off);
            ps[r][0] = p0; ps[r][1] = p1; ps[r][2] = p2; ps[r][3] = p3;
            if (mq == 0) {
                float s = __expf(old - nm);
                mx_s[n] = nm;
                scale_s[n] = s;
                l_s[n] = l_s[n] * s + rs;
            }
        }
        *(float4*)&smA[n2][mq4]     = make_float4(ps[0][0], ps[0][1], ps[0][2], ps[0][3]);
        *(float4*)&smA[n2 + 1][mq4] = make_float4(ps[1][0], ps[1][1], ps[1][2], ps[1][3]);
        __syncthreads();   // p tile + scale_s/l_s visible
        // ---------- rescale accumulators (once per m-tile) ----------
        float sck[4];
        #pragma unroll
        for (int k4 = 0; k4 < 4; ++k4) sck[k4] = scale_s[ng2 + (k4 << 4)];
        #pragma unroll
        for (int q = 0; q < 4; ++q)
            #pragma unroll
            for (int k4 = 0; k4 < 4; ++k4)
                #pragma unroll
                for (int j = 0; j < 4; ++j)
                    acc[q][k4][j] *= sck[k4];
        // ---------- phase 2: PV, 4 chunks of 128 channels ----------
        #pragma unroll
        for (int q = 0; q < 4; ++q) {
            __syncthreads();   // previous chunk (or Cs) fully consumed
            #pragma unroll
            for (int r = 0; r < 4; ++r) {
                int fi = t + (r << 9);
                int cl = fi >> 4;             // 0..127
                int mf = (fi & 15) << 2;      // 0..60
                float4 v = *(const float4*)(Dm + (size_t)((q << 7) + cl) * NN + (m0 + mf));
                smD[mf + 0][cl] = v.x;
                smD[mf + 1][cl] = v.y;
                smD[mf + 2][cl] = v.z;
                smD[mf + 3][cl] = v.w;
            }
            __syncthreads();
            #pragma unroll
            for (int mm = 0; mm < 64; mm += 4) {
                float4 pv0 = *(float4*)&smA[ng2][mm];
                float4 pv1 = *(float4*)&smA[ng2 + 16][mm];
                float4 pv2 = *(float4*)&smA[ng2 + 32][mm];
                float4 pv3 = *(float4*)&smA[ng2 + 48][mm];
                #pragma unroll
                for (int i = 0; i < 4; ++i) {
                    float4 d = *(float4*)&smD[mm + i][ci4];
                    float a0 = (i == 0) ? pv0.x : (i == 1) ? pv0.y : (i == 2) ? pv0.z : pv0.w;
                    float a1 = (i == 0) ? pv1.x : (i == 1) ? pv1.y : (i == 2) ? pv1.z : pv1.w;
                    float a2 = (i == 0) ? pv2.x : (i == 1) ? pv2.y : (i == 2) ? pv2.z : pv2.w;
                    float a3 = (i == 0) ? pv3.x : (i == 1) ? pv3.y : (i == 2) ? pv3.z : pv3.w;
                    acc[q][0][0] += a0 * d.x; acc[q][0][1] += a0 * d.y; acc[q][0][2] += a0 * d.z; acc[q][0][3] += a0 * d.w;
                    acc[q][1][0] += a1 * d.x; acc[q][1][1] += a1 * d.y; acc[q][1][2] += a1 * d.z; acc[q][1][3] += a1 * d.w;
                    acc[q][2][0] += a2 * d.x; acc[q][2][1] += a2 * d.y; acc[q][2][2] += a2 * d.z; acc[q][2][3] += a2 * d.w;
                    acc[q][3][0] += a3 * d.x; acc[q][3][1] += a3 * d.y; acc[q][3][2] += a3 * d.z; acc[q][3][3] += a3 * d.w;
                }
            }
        }
    }
    // ---------- epilogue: out = gamma * acc/l + x ----------
    __syncthreads();
    const float g = gamma_p[0];
    const float* __restrict__ xb = x + (size_t)b * plane;
    float* __restrict__ ob = out + (size_t)b * plane;
    float invl[4];
    #pragma unroll
    for (int k4 = 0; k4 < 4; ++k4) invl[k4] = 1.0f / l_s[ng2 + (k4 << 4)];
    float* const smf = &smD[0][0];   // 128 x 66 transpose buffer (8448 floats, exactly fits)
    #pragma unroll
    for (int q = 0; q < 4; ++q) {
        __syncthreads();
        #pragma unroll
        for (int k4 = 0; k4 < 4; ++k4) {
            #pragma unroll
            for (int j = 0; j < 4; ++j)
                smf[(ci4 + j) * 66 + ng2 + (k4 << 4)] = acc[q][k4][j] * invl[k4];
        }
        __syncthreads();
        #pragma unroll
        for (int r = 0; r < 4; ++r) {
            int fi = t + (r << 9);
            int cr = fi >> 4;             // 0..127
            int n4 = (fi & 15) << 2;
            int cg = (q << 7) + cr;
            float v0 = smf[cr * 66 + n4 + 0];
            float v1 = smf[cr * 66 + n4 + 1];
            float v2 = smf[cr * 66 + n4 + 2];
            float v3 = smf[cr * 66 + n4 + 3];
            float4 xv = *(const float4*)(xb + (size_t)cg * NN + (n0 + n4));
            float4 o;
            o.x = g * v0 + xv.x;
            o.y = g * v1 + xv.y;
            o.z = g * v2 + xv.z;
            o.w = g * v3 + xv.w;
            *(float4*)(ob + (size_t)cg * NN + (n0 + n4)) = o;
        }
    }
}

extern "C" void kernel_launch(void* const* d_in, const int* in_sizes, int n_in,
                              void* d_out, int out_size, void* d_ws, size_t ws_size,
                              hipStream_t stream) {
    const float* x  = (const float*)d_in[0];
    const float* Wb = (const float*)d_in[1];
    const float* Wc = (const float*)d_in[2];
    const float* Wd = (const float*)d_in[3];
    const float* gm = (const float*)d_in[4];
    float* out = (float*)d_out;
    float* ws  = (float*)d_ws;
    // workspace: Bm | Cm | Dm, each BB*CC*NN fp32 = 33.5 MB -> 100.7 MB total
    // (assumes ws_size >= 100663296 bytes)

    dim3 g1(NN / 64, CC / 64, BB * 3);
    proj_gemm<<<g1, 256, 0, stream>>>(x, Wb, Wc, Wd, ws);

    dim3 g2(NN / 64, BB);
    attn_kernel<<<g2, 512, 0, stream>>>(x, gm, ws, out);
}

// Round 2
// 474.556 us; speedup vs baseline: 7.6560x; 7.6560x over previous
//
#include <hip/hip_runtime.h>
#include <math.h>
#include <stdint.h>

#define CC 512
#define NN 4096
#define BB 4

typedef _Float16 f16;
typedef _Float16 f16x8 __attribute__((ext_vector_type(8)));
typedef _Float16 f16x4 __attribute__((ext_vector_type(4)));
typedef float f32x4 __attribute__((ext_vector_type(4)));

// ---------- async global->LDS 16B with addrspace casts ----------
__device__ __forceinline__ void gload_lds16(const void* g, void* l) {
    __builtin_amdgcn_global_load_lds(
        (const __attribute__((address_space(1))) void*)g,
        (__attribute__((address_space(3))) void*)l, 16, 0, 0);
}

// Stage ROWS rows x 64 f16 (8 chunks of 16B) from K-major global into linear LDS.
// Source pre-swizzle: LDS chunk (r,c) holds global chunk (c ^ (r&7)).  [T2 both-sides]
template<int ROWS>
__device__ __forceinline__ void stage_tile(const f16* __restrict__ g, int stride_e,
                                           f16* lds, int wid, int lane) {
    constexpr int ITERS = ROWS * 8 / 64 / 4;   // 4 waves
    #pragma unroll
    for (int it = 0; it < ITERS; ++it) {
        int flatbase = (wid * ITERS + it) * 64;      // wave-uniform
        f16* dst = lds + flatbase * 8;               // lane*16B auto-appended by HW
        int flat = flatbase + lane;
        int r = flat >> 3, c = flat & 7;
        const f16* src = g + (size_t)r * stride_e + ((c ^ (r & 7)) << 3);
        gload_lds16(src, dst);
    }
}

// Swizzled fragment read: row r, chunk ch (8 f16 per chunk)
__device__ __forceinline__ f16x8 frag_ld(const f16* lds, int r, int ch) {
    return *(const f16x8*)(lds + r * 64 + ((ch ^ (r & 7)) << 3));
}

#define MFMA16(a, b, c) __builtin_amdgcn_mfma_f32_16x16x32_f16((a), (b), (c), 0, 0, 0)

// ---------------- W conversion: fp32 -> fp16, K-major (natural) ----------------
__global__ __launch_bounds__(256) void wcvt_k(const float* __restrict__ Wb,
                                              const float* __restrict__ Wc,
                                              const float* __restrict__ Wd,
                                              f16* __restrict__ W16) {
    int i = blockIdx.x * 256 + threadIdx.x;      // one float4 per thread
    int idx = i * 4;                              // 0 .. 3*512*512-4
    int m = idx >> 18;
    int off = idx & 262143;
    const float* src = (m == 0) ? Wb : (m == 1) ? Wc : Wd;
    f32x4 v = *(const f32x4*)(src + off);
    f16x4 h = { (f16)v[0], (f16)v[1], (f16)v[2], (f16)v[3] };
    *(f16x4*)(W16 + idx) = h;
}

// ---------------- proj: O[o][n] = sum_c W[o][c] * x[c][n]  (per batch) ----------------
// wsel 0/1 -> write transposed Bt/Ct [n][c]; wsel 2 -> write Dm [c][n] natural.
__global__ __launch_bounds__(256) void proj_k(const float* __restrict__ x,
                                              const f16* __restrict__ W16,
                                              f16* __restrict__ Bt, f16* __restrict__ Ct,
                                              f16* __restrict__ Dm, int b) {
    const int wsel = blockIdx.z;
    const f16* __restrict__ W = W16 + (size_t)wsel * CC * CC;     // [o][c]
    const float* __restrict__ X = x + (size_t)b * CC * NN;        // [c][n]
    const int o0 = blockIdx.y * 128, n0 = blockIdx.x * 128;

    __shared__ __align__(16) char smraw[34816];
    f16* As = (f16*)smraw;            // W tile  [128 o][64 c]
    f16* Bs = As + 128 * 64;          // x^T tile [128 n][64 c]
    f16* T  = (f16*)smraw;            // epilogue transpose buffer [128][136]

    const int t = threadIdx.x;
    const int wid = t >> 6, lane = t & 63;
    const int wr = wid >> 1, wc = wid & 1;        // wave tile 64(o) x 64(n)

    f32x4 acc[4][4] = {};

    const int cg = t & 7;                 // c-group of 8 rows
    const int n4 = ((t >> 3) & 31) * 4;   // 4 n per thread

    for (int kc = 0; kc < CC; kc += 64) {
        __syncthreads();
        // A: W via async glds (pre-swizzled source)
        stage_tile<128>(W + (size_t)o0 * CC + kc, CC, As, wid, lane);
        // B: x fp32 -> transpose -> fp16 [n][c], swizzled write
        f32x4 v[8];
        #pragma unroll
        for (int i = 0; i < 8; ++i)
            v[i] = *(const f32x4*)(X + (size_t)(kc + cg * 8 + i) * NN + n0 + n4);
        #pragma unroll
        for (int j = 0; j < 4; ++j) {
            f16x8 h = { (f16)v[0][j], (f16)v[1][j], (f16)v[2][j], (f16)v[3][j],
                        (f16)v[4][j], (f16)v[5][j], (f16)v[6][j], (f16)v[7][j] };
            int r = n4 + j;
            *(f16x8*)(Bs + r * 64 + ((cg ^ (r & 7)) << 3)) = h;
        }
        __syncthreads();
        #pragma unroll
        for (int ks = 0; ks < 2; ++ks) {
            int ch = ks * 4 + (lane >> 4);
            f16x8 a[4], bb[4];
            #pragma unroll
            for (int i = 0; i < 4; ++i) a[i]  = frag_ld(As, wr * 64 + i * 16 + (lane & 15), ch);
            #pragma unroll
            for (int j = 0; j < 4; ++j) bb[j] = frag_ld(Bs, wc * 64 + j * 16 + (lane & 15), ch);
            #pragma unroll
            for (int i = 0; i < 4; ++i)
                #pragma unroll
                for (int j = 0; j < 4; ++j)
                    acc[i][j] = MFMA16(a[i], bb[j], acc[i][j]);
        }
    }

    __syncthreads();   // staging buffers dead; reuse as T
    if (wsel < 2) {
        // T[n][o] (transpose), then coalesced rows of Bt/Ct [n][c]
        #pragma unroll
        for (int i = 0; i < 4; ++i)
            #pragma unroll
            for (int j = 0; j < 4; ++j) {
                int n_l = wc * 64 + j * 16 + (lane & 15);
                int o_l = wr * 64 + i * 16 + (lane >> 4) * 4;
                f16x4 h = { (f16)acc[i][j][0], (f16)acc[i][j][1], (f16)acc[i][j][2], (f16)acc[i][j][3] };
                *(f16x4*)(T + n_l * 136 + o_l) = h;
            }
        __syncthreads();
        f16* __restrict__ dst = (wsel == 0) ? Bt : Ct;
        int n = t & 127;
        #pragma unroll
        for (int it = 0; it < 8; ++it) {
            int ch8 = (t >> 7) * 8 + it;  // 0..15
            f16x8 h = *(f16x8*)(T + n * 136 + ch8 * 8);
            *(f16x8*)(dst + (size_t)(n0 + n) * CC + o0 + ch8 * 8) = h;
        }
    } else {
        // T[o][n] (natural), then coalesced rows of Dm [c][n]
        #pragma unroll
        for (int i = 0; i < 4; ++i)
            #pragma unroll
            for (int j = 0; j < 4; ++j) {
                int n_l = wc * 64 + j * 16 + (lane & 15);
                #pragma unroll
                for (int q = 0; q < 4; ++q) {
                    int o_l = wr * 64 + i * 16 + (lane >> 4) * 4 + q;
                    T[o_l * 136 + n_l] = (f16)acc[i][j][q];
                }
            }
        __syncthreads();
        int o = t & 127;
        #pragma unroll
        for (int it = 0; it < 8; ++it) {
            int ch8 = (t >> 7) * 8 + it;
            f16x8 h = *(f16x8*)(T + o * 136 + ch8 * 8);
            *(f16x8*)(Dm + (size_t)(o0 + o) * NN + n0 + ch8 * 8) = h;
        }
    }
}

// ---------------- logits: L[n][m] = sum_c Bt[n][c] * Ct[m][c] ----------------
__global__ __launch_bounds__(256) void logits_k(const f16* __restrict__ Bt,
                                                const f16* __restrict__ Ct,
                                                float* __restrict__ L) {
    const int m0 = blockIdx.x * 128, n0 = blockIdx.y * 128;
    __shared__ __align__(16) f16 As[128 * 64];
    __shared__ __align__(16) f16 Bs[128 * 64];
    const int t = threadIdx.x;
    const int wid = t >> 6, lane = t & 63;
    const int wr = wid >> 1, wc = wid & 1;

    f32x4 acc[4][4] = {};
    for (int kc = 0; kc < CC; kc += 64) {
        __syncthreads();
        stage_tile<128>(Bt + (size_t)n0 * CC + kc, CC, As, wid, lane);
        stage_tile<128>(Ct + (size_t)m0 * CC + kc, CC, Bs, wid, lane);
        __syncthreads();
        #pragma unroll
        for (int ks = 0; ks < 2; ++ks) {
            int ch = ks * 4 + (lane >> 4);
            f16x8 a[4], bb[4];
            #pragma unroll
            for (int i = 0; i < 4; ++i) a[i]  = frag_ld(As, wr * 64 + i * 16 + (lane & 15), ch);
            #pragma unroll
            for (int j = 0; j < 4; ++j) bb[j] = frag_ld(Bs, wc * 64 + j * 16 + (lane & 15), ch);
            #pragma unroll
            for (int i = 0; i < 4; ++i)
                #pragma unroll
                for (int j = 0; j < 4; ++j)
                    acc[i][j] = MFMA16(a[i], bb[j], acc[i][j]);
        }
    }
    // write L fp32 (rows n, cols m); 16-lane segments of 64B
    #pragma unroll
    for (int i = 0; i < 4; ++i)
        #pragma unroll
        for (int j = 0; j < 4; ++j) {
            int col = m0 + wc * 64 + j * 16 + (lane & 15);
            #pragma unroll
            for (int q = 0; q < 4; ++q) {
                int row = n0 + wr * 64 + i * 16 + (lane >> 4) * 4 + q;
                L[(size_t)row * NN + col] = acc[i][j][q];
            }
        }
}

// ---------------- softmax row kernel: P' = exp(L-m) fp16 in place, invl = 1/sum ----------------
__global__ __launch_bounds__(256) void softmax_k(float* __restrict__ L,
                                                 float* __restrict__ invl) {
    const int r = blockIdx.x;
    float* __restrict__ row = L + (size_t)r * NN;
    const int t = threadIdx.x;
    const int wid = t >> 6, lane = t & 63;
    __shared__ float red[8];

    f32x4 v[4];
    #pragma unroll
    for (int it = 0; it < 4; ++it)
        v[it] = *(const f32x4*)(row + (it * 256 + t) * 4);

    float m = -INFINITY;
    #pragma unroll
    for (int it = 0; it < 4; ++it)
        m = fmaxf(m, fmaxf(fmaxf(v[it][0], v[it][1]), fmaxf(v[it][2], v[it][3])));
    #pragma unroll
    for (int off = 1; off < 64; off <<= 1) m = fmaxf(m, __shfl_xor(m, off));
    if (lane == 0) red[wid] = m;
    __syncthreads();
    m = fmaxf(fmaxf(red[0], red[1]), fmaxf(red[2], red[3]));

    float s = 0.f;
    f32x4 p[4];
    #pragma unroll
    for (int it = 0; it < 4; ++it) {
        #pragma unroll
        for (int j = 0; j < 4; ++j) { p[it][j] = __expf(v[it][j] - m); s += p[it][j]; }
    }
    #pragma unroll
    for (int off = 1; off < 64; off <<= 1) s += __shfl_xor(s, off);
    if (lane == 0) red[4 + wid] = s;
    __syncthreads();
    s = red[4] + red[5] + red[6] + red[7];

    f16* __restrict__ prow = (f16*)row;   // in-place: first 8KB of the 16KB row
    #pragma unroll
    for (int it = 0; it < 4; ++it) {
        f16x4 h = { (f16)p[it][0], (f16)p[it][1], (f16)p[it][2], (f16)p[it][3] };
        *(f16x4*)(prow + (it * 256 + t) * 4) = h;
    }
    if (t == 0) invl[r] = 1.0f / s;
}

// ---------------- pv: O[n][c] = sum_m P'[n][m] * Dm[c][m]; out = g*O*invl + x ----------------
__global__ __launch_bounds__(256) void pv_k(const float* __restrict__ x,
                                            const float* __restrict__ gamma_p,
                                            const f16* __restrict__ Dm,
                                            const float* __restrict__ L,
                                            const float* __restrict__ invl,
                                            float* __restrict__ out, int b) {
    const int n0 = blockIdx.x * 64, c0 = blockIdx.y * 128;
    const f16* __restrict__ P = (const f16*)L;    // rows stride 8192 f16 (fp32 row reinterpreted)

    __shared__ __align__(16) char smraw[34816];
    f16* As = (f16*)smraw;            // P tile  [64 n][64 m]
    f16* Bs = As + 64 * 64;           // D tile  [128 c][64 m]
    float* T = (float*)smraw;         // epilogue [128 c][68 n]

    const int t = threadIdx.x;
    const int wid = t >> 6, lane = t & 63;
    const int wr = wid >> 1, wc = wid & 1;        // wave tile 32(n) x 64(c)

    f32x4 acc[2][4] = {};
    for (int mc = 0; mc < NN; mc += 64) {
        __syncthreads();
        stage_tile<64>(P + (size_t)n0 * 8192 + mc, 8192, As, wid, lane);
        stage_tile<128>(Dm + (size_t)c0 * NN + mc, NN, Bs, wid, lane);
        __syncthreads();
        #pragma unroll
        for (int ks = 0; ks < 2; ++ks) {
            int ch = ks * 4 + (lane >> 4);
            f16x8 a[2], bb[4];
            #pragma unroll
            for (int i = 0; i < 2; ++i) a[i]  = frag_ld(As, wr * 32 + i * 16 + (lane & 15), ch);
            #pragma unroll
            for (int j = 0; j < 4; ++j) bb[j] = frag_ld(Bs, wc * 64 + j * 16 + (lane & 15), ch);
            #pragma unroll
            for (int i = 0; i < 2; ++i)
                #pragma unroll
                for (int j = 0; j < 4; ++j)
                    acc[i][j] = MFMA16(a[i], bb[j], acc[i][j]);
        }
    }

    __syncthreads();
    const float g = gamma_p[0];
    // T[c][n] = g * invl[n] * acc
    #pragma unroll
    for (int i = 0; i < 2; ++i) {
        int nb = wr * 32 + i * 16 + (lane >> 4) * 4;
        f32x4 il = *(const f32x4*)(invl + n0 + nb);
        #pragma unroll
        for (int j = 0; j < 4; ++j) {
            int c_l = wc * 64 + j * 16 + (lane & 15);
            f32x4 o;
            #pragma unroll
            for (int q = 0; q < 4; ++q) o[q] = g * il[q] * acc[i][j][q];
            *(f32x4*)(T + c_l * 68 + nb) = o;
        }
    }
    __syncthreads();
    // out[c][n] = T + x
    const float* __restrict__ xb = x + (size_t)b * CC * NN;
    float* __restrict__ ob = out + (size_t)b * CC * NN;
    int c_l = t >> 1, nf = (t & 1) * 32;
    #pragma unroll
    for (int it = 0; it < 8; ++it) {
        f32x4 v = *(const f32x4*)(T + c_l * 68 + nf + it * 4);
        f32x4 xv = *(const f32x4*)(xb + (size_t)(c0 + c_l) * NN + n0 + nf + it * 4);
        #pragma unroll
        for (int q = 0; q < 4; ++q) v[q] += xv[q];
        *(f32x4*)(ob + (size_t)(c0 + c_l) * NN + n0 + nf + it * 4) = v;
    }
}

extern "C" void kernel_launch(void* const* d_in, const int* in_sizes, int n_in,
                              void* d_out, int out_size, void* d_ws, size_t ws_size,
                              hipStream_t stream) {
    const float* x  = (const float*)d_in[0];
    const float* Wb = (const float*)d_in[1];
    const float* Wc = (const float*)d_in[2];
    const float* Wd = (const float*)d_in[3];
    const float* gm = (const float*)d_in[4];
    float* out = (float*)d_out;
    char* ws = (char*)d_ws;

    // ws layout (bytes): W16 1.5MB | Bt 4MB | Ct 4MB | Dm 4MB | L 64MB fp32 | invl 16KB  (~81MB)
    f16*   W16  = (f16*)(ws);
    f16*   Bt   = (f16*)(ws + 1572864);
    f16*   Ct   = (f16*)(ws + 1572864 + 4194304);
    f16*   Dm   = (f16*)(ws + 1572864 + 2 * 4194304);
    float* L    = (float*)(ws + 1572864 + 3 * 4194304);
    float* invl = (float*)(ws + 1572864 + 3 * 4194304 + 67108864);

    wcvt_k<<<dim3(768), 256, 0, stream>>>(Wb, Wc, Wd, W16);

    for (int b = 0; b < BB; ++b) {
        proj_k<<<dim3(32, 4, 3), 256, 0, stream>>>(x, W16, Bt, Ct, Dm, b);
        logits_k<<<dim3(32, 32), 256, 0, stream>>>(Bt, Ct, L);
        softmax_k<<<dim3(4096), 256, 0, stream>>>(L, invl);
        pv_k<<<dim3(64, 4), 256, 0, stream>>>(x, gm, Dm, L, invl, out, b);
    }
}

// Round 3
// 425.222 us; speedup vs baseline: 8.5443x; 1.1160x over previous
//
#include <hip/hip_runtime.h>
#include <math.h>
#include <stdint.h>

#define CC 512
#define NN 4096
#define BB 4

typedef _Float16 f16;
typedef _Float16 f16x8 __attribute__((ext_vector_type(8)));
typedef _Float16 f16x4 __attribute__((ext_vector_type(4)));
typedef float f32x4 __attribute__((ext_vector_type(4)));

// ---------- async global->LDS 16B with addrspace casts ----------
__device__ __forceinline__ void gload_lds16(const void* g, void* l) {
    __builtin_amdgcn_global_load_lds(
        (const __attribute__((address_space(1))) void*)g,
        (__attribute__((address_space(3))) void*)l, 16, 0, 0);
}

// Stage ROWS rows x 64 f16 (8 chunks of 16B) from K-major global into linear LDS.
// Source pre-swizzle: LDS chunk (r,c) holds global chunk (c ^ (r&7)).  [T2 both-sides]
template<int ROWS>
__device__ __forceinline__ void stage_tile(const f16* __restrict__ g, int stride_e,
                                           f16* lds, int wid, int lane) {
    constexpr int ITERS = ROWS * 8 / 64 / 4;   // 4 waves
    #pragma unroll
    for (int it = 0; it < ITERS; ++it) {
        int flatbase = (wid * ITERS + it) * 64;      // wave-uniform
        f16* dst = lds + flatbase * 8;               // lane*16B auto-appended by HW
        int flat = flatbase + lane;
        int r = flat >> 3, c = flat & 7;
        const f16* src = g + (size_t)r * stride_e + ((c ^ (r & 7)) << 3);
        gload_lds16(src, dst);
    }
}

// Swizzled fragment read: row r, chunk ch (8 f16 per chunk)
__device__ __forceinline__ f16x8 frag_ld(const f16* lds, int r, int ch) {
    return *(const f16x8*)(lds + r * 64 + ((ch ^ (r & 7)) << 3));
}

#define MFMA16(a, b, c) __builtin_amdgcn_mfma_f32_16x16x32_f16((a), (b), (c), 0, 0, 0)

// ---------------- W conversion: fp32 -> fp16, K-major (natural) ----------------
__global__ __launch_bounds__(256) void wcvt_k(const float* __restrict__ Wb,
                                              const float* __restrict__ Wc,
                                              const float* __restrict__ Wd,
                                              f16* __restrict__ W16) {
    int i = blockIdx.x * 256 + threadIdx.x;      // one float4 per thread
    int idx = i * 4;                              // 0 .. 3*512*512-4
    int m = idx >> 18;
    int off = idx & 262143;
    const float* src = (m == 0) ? Wb : (m == 1) ? Wc : Wd;
    f32x4 v = *(const f32x4*)(src + off);
    f16x4 h = { (f16)v[0], (f16)v[1], (f16)v[2], (f16)v[3] };
    *(f16x4*)(W16 + idx) = h;
}

// ---------------- proj: O[o][n] = sum_c W[o][c] * x[c][n]  (per batch) ----------------
// wsel 0/1 -> write transposed Bt/Ct [n][c]; wsel 2 -> write Dm [c][n] natural.
__global__ __launch_bounds__(256) void proj_k(const float* __restrict__ x,
                                              const f16* __restrict__ W16,
                                              f16* __restrict__ Bt, f16* __restrict__ Ct,
                                              f16* __restrict__ Dm, int b) {
    const int wsel = blockIdx.z;
    const f16* __restrict__ W = W16 + (size_t)wsel * CC * CC;     // [o][c]
    const float* __restrict__ X = x + (size_t)b * CC * NN;        // [c][n]
    const int o0 = blockIdx.y * 128, n0 = blockIdx.x * 128;

    __shared__ __align__(16) char smraw[34816];
    f16* As = (f16*)smraw;            // W tile  [128 o][64 c]
    f16* Bs = As + 128 * 64;          // x^T tile [128 n][64 c]
    f16* T  = (f16*)smraw;            // epilogue transpose buffer [128][136]

    const int t = threadIdx.x;
    const int wid = t >> 6, lane = t & 63;
    const int wr = wid >> 1, wc = wid & 1;        // wave tile 64(o) x 64(n)

    f32x4 acc[4][4] = {};

    const int cg = t & 7;                 // c-group of 8 rows
    const int n4 = ((t >> 3) & 31) * 4;   // 4 n per thread

    for (int kc = 0; kc < CC; kc += 64) {
        __syncthreads();
        // A: W via async glds (pre-swizzled source)
        stage_tile<128>(W + (size_t)o0 * CC + kc, CC, As, wid, lane);
        // B: x fp32 -> transpose -> fp16 [n][c], swizzled write
        f32x4 v[8];
        #pragma unroll
        for (int i = 0; i < 8; ++i)
            v[i] = *(const f32x4*)(X + (size_t)(kc + cg * 8 + i) * NN + n0 + n4);
        #pragma unroll
        for (int j = 0; j < 4; ++j) {
            f16x8 h = { (f16)v[0][j], (f16)v[1][j], (f16)v[2][j], (f16)v[3][j],
                        (f16)v[4][j], (f16)v[5][j], (f16)v[6][j], (f16)v[7][j] };
            int r = n4 + j;
            *(f16x8*)(Bs + r * 64 + ((cg ^ (r & 7)) << 3)) = h;
        }
        __syncthreads();
        #pragma unroll
        for (int ks = 0; ks < 2; ++ks) {
            int ch = ks * 4 + (lane >> 4);
            f16x8 a[4], bb[4];
            #pragma unroll
            for (int i = 0; i < 4; ++i) a[i]  = frag_ld(As, wr * 64 + i * 16 + (lane & 15), ch);
            #pragma unroll
            for (int j = 0; j < 4; ++j) bb[j] = frag_ld(Bs, wc * 64 + j * 16 + (lane & 15), ch);
            #pragma unroll
            for (int i = 0; i < 4; ++i)
                #pragma unroll
                for (int j = 0; j < 4; ++j)
                    acc[i][j] = MFMA16(a[i], bb[j], acc[i][j]);
        }
    }

    __syncthreads();   // staging buffers dead; reuse as T
    if (wsel < 2) {
        // T[n][o] (transpose), then coalesced rows of Bt/Ct [n][c]
        #pragma unroll
        for (int i = 0; i < 4; ++i)
            #pragma unroll
            for (int j = 0; j < 4; ++j) {
                int n_l = wc * 64 + j * 16 + (lane & 15);
                int o_l = wr * 64 + i * 16 + (lane >> 4) * 4;
                f16x4 h = { (f16)acc[i][j][0], (f16)acc[i][j][1], (f16)acc[i][j][2], (f16)acc[i][j][3] };
                *(f16x4*)(T + n_l * 136 + o_l) = h;
            }
        __syncthreads();
        f16* __restrict__ dst = (wsel == 0) ? Bt : Ct;
        int n = t & 127;
        #pragma unroll
        for (int it = 0; it < 8; ++it) {
            int ch8 = (t >> 7) * 8 + it;  // 0..15
            f16x8 h = *(f16x8*)(T + n * 136 + ch8 * 8);
            *(f16x8*)(dst + (size_t)(n0 + n) * CC + o0 + ch8 * 8) = h;
        }
    } else {
        // T[o][n] (natural), then coalesced rows of Dm [c][n]
        #pragma unroll
        for (int i = 0; i < 4; ++i)
            #pragma unroll
            for (int j = 0; j < 4; ++j) {
                int n_l = wc * 64 + j * 16 + (lane & 15);
                #pragma unroll
                for (int q = 0; q < 4; ++q) {
                    int o_l = wr * 64 + i * 16 + (lane >> 4) * 4 + q;
                    T[o_l * 136 + n_l] = (f16)acc[i][j][q];
                }
            }
        __syncthreads();
        int o = t & 127;
        #pragma unroll
        for (int it = 0; it < 8; ++it) {
            int ch8 = (t >> 7) * 8 + it;
            f16x8 h = *(f16x8*)(T + o * 136 + ch8 * 8);
            *(f16x8*)(Dm + (size_t)(o0 + o) * NN + n0 + ch8 * 8) = h;
        }
    }
}

// ---------------- logits: L[n][m] = sum_c Bt[n][c] * Ct[m][c] ----------------
__global__ __launch_bounds__(256) void logits_k(const f16* __restrict__ Bt,
                                                const f16* __restrict__ Ct,
                                                float* __restrict__ L) {
    // XCD-aware bijective swizzle: 1024 blocks = 8 XCDs x 128
    int lin = blockIdx.x + 32 * blockIdx.y;
    int wg = (lin & 7) * 128 + (lin >> 3);
    const int m0 = (wg & 31) * 128;
    const int n0 = (wg >> 5) * 128;

    __shared__ __align__(16) f16 As[128 * 64];
    __shared__ __align__(16) f16 Bs[128 * 64];
    const int t = threadIdx.x;
    const int wid = t >> 6, lane = t & 63;
    const int wr = wid >> 1, wc = wid & 1;

    f32x4 acc[4][4] = {};
    for (int kc = 0; kc < CC; kc += 64) {
        __syncthreads();
        stage_tile<128>(Bt + (size_t)n0 * CC + kc, CC, As, wid, lane);
        stage_tile<128>(Ct + (size_t)m0 * CC + kc, CC, Bs, wid, lane);
        __syncthreads();
        #pragma unroll
        for (int ks = 0; ks < 2; ++ks) {
            int ch = ks * 4 + (lane >> 4);
            f16x8 a[4], bb[4];
            #pragma unroll
            for (int i = 0; i < 4; ++i) a[i]  = frag_ld(As, wr * 64 + i * 16 + (lane & 15), ch);
            #pragma unroll
            for (int j = 0; j < 4; ++j) bb[j] = frag_ld(Bs, wc * 64 + j * 16 + (lane & 15), ch);
            #pragma unroll
            for (int i = 0; i < 4; ++i)
                #pragma unroll
                for (int j = 0; j < 4; ++j)
                    acc[i][j] = MFMA16(a[i], bb[j], acc[i][j]);
        }
    }
    // write L fp32 (rows n, cols m); 16-lane segments of 64B
    #pragma unroll
    for (int i = 0; i < 4; ++i)
        #pragma unroll
        for (int j = 0; j < 4; ++j) {
            int col = m0 + wc * 64 + j * 16 + (lane & 15);
            #pragma unroll
            for (int q = 0; q < 4; ++q) {
                int row = n0 + wr * 64 + i * 16 + (lane >> 4) * 4 + q;
                L[(size_t)row * NN + col] = acc[i][j][q];
            }
        }
}

// ---------------- softmax row kernel: P' = exp(L-m) fp16 in place, invl = 1/sum ----------------
__global__ __launch_bounds__(256) void softmax_k(float* __restrict__ L,
                                                 float* __restrict__ invl) {
    const int r = blockIdx.x;
    float* __restrict__ row = L + (size_t)r * NN;
    const int t = threadIdx.x;
    const int wid = t >> 6, lane = t & 63;
    __shared__ float red[8];

    f32x4 v[4];
    #pragma unroll
    for (int it = 0; it < 4; ++it)
        v[it] = *(const f32x4*)(row + (it * 256 + t) * 4);

    float m = -INFINITY;
    #pragma unroll
    for (int it = 0; it < 4; ++it)
        m = fmaxf(m, fmaxf(fmaxf(v[it][0], v[it][1]), fmaxf(v[it][2], v[it][3])));
    #pragma unroll
    for (int off = 1; off < 64; off <<= 1) m = fmaxf(m, __shfl_xor(m, off));
    if (lane == 0) red[wid] = m;
    __syncthreads();
    m = fmaxf(fmaxf(red[0], red[1]), fmaxf(red[2], red[3]));

    float s = 0.f;
    f32x4 p[4];
    #pragma unroll
    for (int it = 0; it < 4; ++it) {
        #pragma unroll
        for (int j = 0; j < 4; ++j) { p[it][j] = __expf(v[it][j] - m); s += p[it][j]; }
    }
    #pragma unroll
    for (int off = 1; off < 64; off <<= 1) s += __shfl_xor(s, off);
    if (lane == 0) red[4 + wid] = s;
    __syncthreads();
    s = red[4] + red[5] + red[6] + red[7];

    f16* __restrict__ prow = (f16*)row;   // in-place: first 8KB of the 16KB row
    #pragma unroll
    for (int it = 0; it < 4; ++it) {
        f16x4 h = { (f16)p[it][0], (f16)p[it][1], (f16)p[it][2], (f16)p[it][3] };
        *(f16x4*)(prow + (it * 256 + t) * 4) = h;
    }
    if (t == 0) invl[r] = 1.0f / s;
}

// ---------------- pv: split-K partials. Opart[ks][c][n] (fp16) = sum_{m in chunk ks} P'[n][m]*Dm[c][m] ----------------
__global__ __launch_bounds__(256) void pv_k(const f16* __restrict__ Dm,
                                            const float* __restrict__ L,
                                            f16* __restrict__ Opart) {
    // XCD-aware bijective swizzle: 512 blocks = 8 XCDs x 64
    int lin = blockIdx.x + 32 * blockIdx.y + 128 * blockIdx.z;
    int wg = (lin & 7) * 64 + (lin >> 3);
    const int n0 = (wg & 31) * 128;
    const int c0 = ((wg >> 5) & 3) * 128;
    const int ks = wg >> 7;
    const int m_off = ks * 1024;

    const f16* __restrict__ P = (const f16*)L;   // row stride 8192 f16 (fp32 row reinterpreted)

    __shared__ __align__(16) char smraw[34816];
    f16* As = (f16*)smraw;            // P tile [128 n][64 m]
    f16* Bs = As + 128 * 64;          // D tile [128 c][64 m]
    f16* T  = (f16*)smraw;            // epilogue transpose buffer [128 c][136 n]

    const int t = threadIdx.x;
    const int wid = t >> 6, lane = t & 63;
    const int wr = wid >> 1, wc = wid & 1;        // wave tile 64(n) x 64(c)

    f32x4 acc[4][4] = {};
    for (int mc = 0; mc < 1024; mc += 64) {
        __syncthreads();
        stage_tile<128>(P + (size_t)n0 * 8192 + m_off + mc, 8192, As, wid, lane);
        stage_tile<128>(Dm + (size_t)c0 * (size_t)NN + m_off + mc, NN, Bs, wid, lane);
        __syncthreads();
        #pragma unroll
        for (int ks2 = 0; ks2 < 2; ++ks2) {
            int ch = ks2 * 4 + (lane >> 4);
            f16x8 a[4], bb[4];
            #pragma unroll
            for (int i = 0; i < 4; ++i) a[i]  = frag_ld(As, wr * 64 + i * 16 + (lane & 15), ch);
            #pragma unroll
            for (int j = 0; j < 4; ++j) bb[j] = frag_ld(Bs, wc * 64 + j * 16 + (lane & 15), ch);
            #pragma unroll
            for (int i = 0; i < 4; ++i)
                #pragma unroll
                for (int j = 0; j < 4; ++j)
                    acc[i][j] = MFMA16(a[i], bb[j], acc[i][j]);
        }
    }

    __syncthreads();
    // T[c][n] = acc (fp16)
    #pragma unroll
    for (int i = 0; i < 4; ++i)
        #pragma unroll
        for (int j = 0; j < 4; ++j) {
            int c_l = wc * 64 + j * 16 + (lane & 15);
            int n_l = wr * 64 + i * 16 + (lane >> 4) * 4;
            f16x4 h = { (f16)acc[i][j][0], (f16)acc[i][j][1], (f16)acc[i][j][2], (f16)acc[i][j][3] };
            *(f16x4*)(T + c_l * 136 + n_l) = h;
        }
    __syncthreads();
    // coalesced copy to Opart[ks][c][n]
    f16* __restrict__ dst = Opart + (size_t)ks * (CC * NN) + (size_t)c0 * NN + n0;
    int cr = t >> 1, half = t & 1;
    #pragma unroll
    for (int k = 0; k < 8; ++k) {
        f16x8 v = *(f16x8*)(T + cr * 136 + half * 64 + k * 8);
        *(f16x8*)(dst + (size_t)cr * NN + half * 64 + k * 8) = v;
    }
}

// ---------------- reduce: out = gamma * invl[n] * sum_ks Opart + x ----------------
__global__ __launch_bounds__(256) void reduce_k(const float* __restrict__ x,
                                                const float* __restrict__ gamma_p,
                                                const f16* __restrict__ Opart,
                                                const float* __restrict__ invl,
                                                float* __restrict__ out, int b) {
    int i = blockIdx.x * 256 + threadIdx.x;   // 0 .. 262143
    int e0 = i * 8;
    int c = e0 >> 12;
    int n = e0 & 4095;
    const f16* base = Opart + (size_t)c * NN + n;
    f16x8 p0 = *(const f16x8*)(base);
    f16x8 p1 = *(const f16x8*)(base + (size_t)CC * NN);
    f16x8 p2 = *(const f16x8*)(base + (size_t)2 * CC * NN);
    f16x8 p3 = *(const f16x8*)(base + (size_t)3 * CC * NN);
    const float g = gamma_p[0];
    const float* __restrict__ xb = x + (size_t)b * CC * NN + (size_t)c * NN + n;
    float* __restrict__ ob = out + (size_t)b * CC * NN + (size_t)c * NN + n;
    f32x4 il0 = *(const f32x4*)(invl + n);
    f32x4 il1 = *(const f32x4*)(invl + n + 4);
    f32x4 x0 = *(const f32x4*)(xb);
    f32x4 x1 = *(const f32x4*)(xb + 4);
    f32x4 o0, o1;
    #pragma unroll
    for (int j = 0; j < 4; ++j) {
        float s = (float)p0[j] + (float)p1[j] + (float)p2[j] + (float)p3[j];
        o0[j] = g * il0[j] * s + x0[j];
    }
    #pragma unroll
    for (int j = 0; j < 4; ++j) {
        float s = (float)p0[j + 4] + (float)p1[j + 4] + (float)p2[j + 4] + (float)p3[j + 4];
        o1[j] = g * il1[j] * s + x1[j];
    }
    *(f32x4*)(ob) = o0;
    *(f32x4*)(ob + 4) = o1;
}

extern "C" void kernel_launch(void* const* d_in, const int* in_sizes, int n_in,
                              void* d_out, int out_size, void* d_ws, size_t ws_size,
                              hipStream_t stream) {
    const float* x  = (const float*)d_in[0];
    const float* Wb = (const float*)d_in[1];
    const float* Wc = (const float*)d_in[2];
    const float* Wd = (const float*)d_in[3];
    const float* gm = (const float*)d_in[4];
    float* out = (float*)d_out;
    char* ws = (char*)d_ws;

    // ws layout (bytes): W16 1.5MB | Bt 4MB | Ct 4MB | Dm 4MB | L 64MB fp32 | invl 16KB | Opart 16MB (~98MB)
    f16*   W16   = (f16*)(ws);
    f16*   Bt    = (f16*)(ws + 1572864);
    f16*   Ct    = (f16*)(ws + 1572864 + 4194304);
    f16*   Dm    = (f16*)(ws + 1572864 + 2 * 4194304);
    float* L     = (float*)(ws + 1572864 + 3 * 4194304);
    float* invl  = (float*)(ws + 1572864 + 3 * 4194304 + 67108864);
    f16*   Opart = (f16*)(ws + 1572864 + 3 * 4194304 + 67108864 + 16384);

    wcvt_k<<<dim3(768), 256, 0, stream>>>(Wb, Wc, Wd, W16);

    for (int b = 0; b < BB; ++b) {
        proj_k<<<dim3(32, 4, 3), 256, 0, stream>>>(x, W16, Bt, Ct, Dm, b);
        logits_k<<<dim3(32, 32), 256, 0, stream>>>(Bt, Ct, L);
        softmax_k<<<dim3(4096), 256, 0, stream>>>(L, invl);
        pv_k<<<dim3(32, 4, 4), 256, 0, stream>>>(Dm, L, Opart);
        reduce_k<<<dim3(1024), 256, 0, stream>>>(x, gm, Opart, invl, out, b);
    }
}

// Round 4
// 385.534 us; speedup vs baseline: 9.4238x; 1.1029x over previous
//
#include <hip/hip_runtime.h>
#include <math.h>
#include <stdint.h>

#define CC 512
#define NN 4096
#define BB 4

typedef _Float16 f16;
typedef _Float16 f16x8 __attribute__((ext_vector_type(8)));
typedef _Float16 f16x4 __attribute__((ext_vector_type(4)));
typedef float f32x4 __attribute__((ext_vector_type(4)));

// ---------- async global->LDS 16B ----------
__device__ __forceinline__ void gload_lds16(const void* g, void* l) {
    __builtin_amdgcn_global_load_lds(
        (const __attribute__((address_space(1))) void*)g,
        (__attribute__((address_space(3))) void*)l, 16, 0, 0);
}

// Stage ROWS rows x 64 f16 from K-major global into linear LDS; source pre-swizzled.
template<int ROWS>
__device__ __forceinline__ void stage_tile(const f16* __restrict__ g, int stride_e,
                                           f16* lds, int wid, int lane) {
    constexpr int ITERS = ROWS * 8 / 64 / 4;   // 4 waves
    #pragma unroll
    for (int it = 0; it < ITERS; ++it) {
        int flatbase = (wid * ITERS + it) * 64;
        f16* dst = lds + flatbase * 8;
        int flat = flatbase + lane;
        int r = flat >> 3, c = flat & 7;
        const f16* src = g + (size_t)r * stride_e + ((c ^ (r & 7)) << 3);
        gload_lds16(src, dst);
    }
}

__device__ __forceinline__ f16x8 frag_ld(const f16* lds, int r, int ch) {
    return *(const f16x8*)(lds + r * 64 + ((ch ^ (r & 7)) << 3));
}

#define MFMA16(a, b, c) __builtin_amdgcn_mfma_f32_16x16x32_f16((a), (b), (c), 0, 0, 0)

__device__ __forceinline__ f32x4 redmax16(f32x4 v) {
    #pragma unroll
    for (int off = 1; off < 16; off <<= 1) {
        f32x4 o;
        #pragma unroll
        for (int q = 0; q < 4; ++q) o[q] = __shfl_xor(v[q], off);
        #pragma unroll
        for (int q = 0; q < 4; ++q) v[q] = fmaxf(v[q], o[q]);
    }
    return v;
}
__device__ __forceinline__ f32x4 redsum16(f32x4 v) {
    #pragma unroll
    for (int off = 1; off < 16; off <<= 1) {
        f32x4 o;
        #pragma unroll
        for (int q = 0; q < 4; ++q) o[q] = __shfl_xor(v[q], off);
        #pragma unroll
        for (int q = 0; q < 4; ++q) v[q] += o[q];
    }
    return v;
}

// ---------------- W conversion ----------------
__global__ __launch_bounds__(256) void wcvt_k(const float* __restrict__ Wb,
                                              const float* __restrict__ Wc,
                                              const float* __restrict__ Wd,
                                              f16* __restrict__ W16) {
    int i = blockIdx.x * 256 + threadIdx.x;
    int idx = i * 4;
    int m = idx >> 18;
    int off = idx & 262143;
    const float* src = (m == 0) ? Wb : (m == 1) ? Wc : Wd;
    f32x4 v = *(const f32x4*)(src + off);
    f16x4 h = { (f16)v[0], (f16)v[1], (f16)v[2], (f16)v[3] };
    *(f16x4*)(W16 + idx) = h;
}

// ---------------- proj (all batches): O = W @ x ----------------
__global__ __launch_bounds__(256) void proj_k(const float* __restrict__ x,
                                              const f16* __restrict__ W16,
                                              f16* __restrict__ Bt, f16* __restrict__ Ct,
                                              f16* __restrict__ Dm) {
    const int wsel = blockIdx.z % 3;
    const int b = blockIdx.z / 3;
    const f16* __restrict__ W = W16 + (size_t)wsel * CC * CC;
    const float* __restrict__ X = x + (size_t)b * CC * NN;
    const size_t p16 = (size_t)CC * NN;
    const int o0 = blockIdx.y * 128, n0 = blockIdx.x * 128;

    __shared__ __align__(16) char smraw[34816];
    f16* As = (f16*)smraw;
    f16* Bs = As + 128 * 64;
    f16* T  = (f16*)smraw;

    const int t = threadIdx.x;
    const int wid = t >> 6, lane = t & 63;
    const int wr = wid >> 1, wc = wid & 1;

    f32x4 acc[4][4] = {};
    const int cg = t & 7;
    const int n4 = ((t >> 3) & 31) * 4;

    for (int kc = 0; kc < CC; kc += 64) {
        __syncthreads();
        stage_tile<128>(W + (size_t)o0 * CC + kc, CC, As, wid, lane);
        f32x4 v[8];
        #pragma unroll
        for (int i = 0; i < 8; ++i)
            v[i] = *(const f32x4*)(X + (size_t)(kc + cg * 8 + i) * NN + n0 + n4);
        #pragma unroll
        for (int j = 0; j < 4; ++j) {
            f16x8 h = { (f16)v[0][j], (f16)v[1][j], (f16)v[2][j], (f16)v[3][j],
                        (f16)v[4][j], (f16)v[5][j], (f16)v[6][j], (f16)v[7][j] };
            int r = n4 + j;
            *(f16x8*)(Bs + r * 64 + ((cg ^ (r & 7)) << 3)) = h;
        }
        __syncthreads();
        #pragma unroll
        for (int ks = 0; ks < 2; ++ks) {
            int ch = ks * 4 + (lane >> 4);
            f16x8 a[4], bb[4];
            #pragma unroll
            for (int i = 0; i < 4; ++i) a[i]  = frag_ld(As, wr * 64 + i * 16 + (lane & 15), ch);
            #pragma unroll
            for (int j = 0; j < 4; ++j) bb[j] = frag_ld(Bs, wc * 64 + j * 16 + (lane & 15), ch);
            #pragma unroll
            for (int i = 0; i < 4; ++i)
                #pragma unroll
                for (int j = 0; j < 4; ++j)
                    acc[i][j] = MFMA16(a[i], bb[j], acc[i][j]);
        }
    }

    __syncthreads();
    if (wsel < 2) {
        #pragma unroll
        for (int i = 0; i < 4; ++i)
            #pragma unroll
            for (int j = 0; j < 4; ++j) {
                int n_l = wc * 64 + j * 16 + (lane & 15);
                int o_l = wr * 64 + i * 16 + (lane >> 4) * 4;
                f16x4 h = { (f16)acc[i][j][0], (f16)acc[i][j][1], (f16)acc[i][j][2], (f16)acc[i][j][3] };
                *(f16x4*)(T + n_l * 136 + o_l) = h;
            }
        __syncthreads();
        f16* __restrict__ dst = ((wsel == 0) ? Bt : Ct) + (size_t)b * p16;
        int n = t & 127;
        #pragma unroll
        for (int it = 0; it < 8; ++it) {
            int ch8 = (t >> 7) * 8 + it;
            f16x8 h = *(f16x8*)(T + n * 136 + ch8 * 8);
            *(f16x8*)(dst + (size_t)(n0 + n) * CC + o0 + ch8 * 8) = h;
        }
    } else {
        #pragma unroll
        for (int i = 0; i < 4; ++i)
            #pragma unroll
            for (int j = 0; j < 4; ++j) {
                int n_l = wc * 64 + j * 16 + (lane & 15);
                #pragma unroll
                for (int q = 0; q < 4; ++q) {
                    int o_l = wr * 64 + i * 16 + (lane >> 4) * 4 + q;
                    T[o_l * 136 + n_l] = (f16)acc[i][j][q];
                }
            }
        __syncthreads();
        f16* __restrict__ dst = Dm + (size_t)b * p16;
        int o = t & 127;
        #pragma unroll
        for (int it = 0; it < 8; ++it) {
            int ch8 = (t >> 7) * 8 + it;
            f16x8 h = *(f16x8*)(T + o * 136 + ch8 * 8);
            *(f16x8*)(dst + (size_t)(o0 + o) * NN + n0 + ch8 * 8) = h;
        }
    }
}

// ---------------- fused flash attention: softmax(Bt Ct^T) @ D^T, + residual ----------------
// Block: one (batch, 64-row n-tile). 512 threads, 8 waves: wr=wid>>1 (n quarter), w1=wid&1
// (m-half in QK^T / c-half in PV). Q in regs, O 64n x 512c fp32 in regs.
__global__ __launch_bounds__(512, 2) void flash_k(
    const float* __restrict__ x, const float* __restrict__ gamma_p,
    const f16* __restrict__ Bt, const f16* __restrict__ Ct,
    const f16* __restrict__ Dm, float* __restrict__ out)
{
    __shared__ __align__(16) char sm[140288];
    f16* CtS = (f16*)sm;                       // [64 m][512 K]   65536 B
    f16* DtS = (f16*)(sm + 65536);             // [512 c][64 m]   65536 B
    f16* PS  = (f16*)(sm + 131072);            // [64 n][64 m]     8192 B
    float* mxp = (float*)(sm + 139264);        // [2][64]
    float* lp  = (float*)(sm + 139776);        // [2][64]

    // XCD-pair swizzle: 256 blocks; xcd = bx&7 -> batch (xcd>>1), tile-half (xcd&1)
    const int bx = blockIdx.x;
    const int j8 = bx & 7;
    const int b = j8 >> 1;
    const int n0 = ((bx >> 3) + (j8 & 1) * 32) * 64;

    const size_t p16 = (size_t)CC * NN;
    const f16* __restrict__ Btb = Bt + (size_t)b * p16;   // [n][c]
    const f16* __restrict__ Ctb = Ct + (size_t)b * p16;   // [m][c]
    const f16* __restrict__ Dmb = Dm + (size_t)b * p16;   // [c][m]

    const int t = threadIdx.x;
    const int wid = t >> 6, lane = t & 63;
    const int wr = wid >> 1, w1 = wid & 1;
    const int l15 = lane & 15, g = lane >> 4;

    // Q fragments: rows wr*16+l15, K chunk s*32 + g*8
    f16x8 Q[16];
    {
        const f16* qrow = Btb + (size_t)(n0 + wr * 16 + l15) * CC + g * 8;
        #pragma unroll
        for (int s = 0; s < 16; ++s) Q[s] = *(const f16x8*)(qrow + s * 32);
    }

    f32x4 O[16];
    #pragma unroll
    for (int i = 0; i < 16; ++i) O[i] = (f32x4)(0.f);
    f32x4 m_run = (f32x4)(-INFINITY);
    f32x4 l_run = (f32x4)(0.f);

    for (int m0 = 0; m0 < NN; m0 += 64) {
        __syncthreads();                       // prev iter fully consumed staging+P
        // stage Ct chunk: one 512-f16 row per wave-iter (src pre-swizzled in 128B groups)
        #pragma unroll
        for (int it = 0; it < 8; ++it) {
            int r = wid * 8 + it;
            f16* dst = CtS + r * 512;          // wave-uniform base
            const f16* src = Ctb + (size_t)(m0 + r) * CC + ((lane ^ (r & 7)) << 3);
            gload_lds16(src, dst);
        }
        // stage Dt: [512 c][64 m]
        #pragma unroll
        for (int it = 0; it < 8; ++it) {
            int flatbase = (wid * 8 + it) * 64;
            f16* dst = DtS + flatbase * 8;
            int flat = flatbase + lane;
            int r = flat >> 3, c = flat & 7;
            const f16* src = Dmb + (size_t)r * NN + m0 + ((c ^ (r & 7)) << 3);
            gload_lds16(src, dst);
        }
        __syncthreads();                       // staged data visible

        // QK^T: wave tile 16n x 32m (frags f=0,1)
        f32x4 S0 = (f32x4)(0.f), S1 = (f32x4)(0.f);
        #pragma unroll
        for (int s = 0; s < 16; ++s) {
            int ch = s * 4 + g;
            int mr0 = w1 * 32 + l15;
            int mr1 = mr0 + 16;
            f16x8 b0 = *(const f16x8*)(CtS + mr0 * 512 + (((ch ^ (mr0 & 7)) & 63) << 3));
            f16x8 b1 = *(const f16x8*)(CtS + mr1 * 512 + (((ch ^ (mr1 & 7)) & 63) << 3));
            S0 = MFMA16(Q[s], b0, S0);
            S1 = MFMA16(Q[s], b1, S1);
        }
        // wave-tile row max (rows g*4+q), exchange across m-halves
        f32x4 tm;
        #pragma unroll
        for (int q = 0; q < 4; ++q) tm[q] = fmaxf(S0[q], S1[q]);
        tm = redmax16(tm);
        if (l15 == 0) *(f32x4*)(mxp + w1 * 64 + wr * 16 + g * 4) = tm;
        __syncthreads();
        f32x4 t0 = *(const f32x4*)(mxp + wr * 16 + g * 4);
        f32x4 t1 = *(const f32x4*)(mxp + 64 + wr * 16 + g * 4);
        f32x4 mnew, scl, p0, p1, ps;
        #pragma unroll
        for (int q = 0; q < 4; ++q) {
            mnew[q] = fmaxf(m_run[q], fmaxf(t0[q], t1[q]));
            scl[q] = __expf(m_run[q] - mnew[q]);
            p0[q] = __expf(S0[q] - mnew[q]);
            p1[q] = __expf(S1[q] - mnew[q]);
            ps[q] = p0[q] + p1[q];
        }
        m_run = mnew;
        ps = redsum16(ps);
        if (l15 == 0) *(f32x4*)(lp + w1 * 64 + wr * 16 + g * 4) = ps;
        // write P (f16) swizzled
        #pragma unroll
        for (int q = 0; q < 4; ++q) {
            int row = wr * 16 + g * 4 + q;
            int c0 = w1 * 32 + l15;
            int c1 = c0 + 16;
            PS[row * 64 + ((((c0 >> 3) ^ (row & 7)) << 3) | (c0 & 7))] = (f16)p0[q];
            PS[row * 64 + ((((c1 >> 3) ^ (row & 7)) << 3) | (c1 & 7))] = (f16)p1[q];
        }
        __syncthreads();                       // P + lp visible
        f32x4 lp0 = *(const f32x4*)(lp + wr * 16 + g * 4);
        f32x4 lp1 = *(const f32x4*)(lp + 64 + wr * 16 + g * 4);
        #pragma unroll
        for (int q = 0; q < 4; ++q) l_run[q] = l_run[q] * scl[q] + lp0[q] + lp1[q];
        // O rescale + PV: wave tile 16n x 256c (w1 = c-half)
        #pragma unroll
        for (int i = 0; i < 16; ++i)
            #pragma unroll
            for (int q = 0; q < 4; ++q) O[i][q] *= scl[q];
        int prow = wr * 16 + l15;
        f16x8 pa0 = *(const f16x8*)(PS + prow * 64 + (((g ^ (prow & 7)) & 7) << 3));
        f16x8 pa1 = *(const f16x8*)(PS + prow * 64 + ((((4 + g) ^ (prow & 7)) & 7) << 3));
        #pragma unroll
        for (int jj = 0; jj < 16; ++jj) {
            int crow = w1 * 256 + jj * 16 + l15;
            f16x8 d0 = *(const f16x8*)(DtS + crow * 64 + (((g ^ (crow & 7)) & 7) << 3));
            f16x8 d1 = *(const f16x8*)(DtS + crow * 64 + ((((4 + g) ^ (crow & 7)) & 7) << 3));
            O[jj] = MFMA16(pa0, d0, O[jj]);
            O[jj] = MFMA16(pa1, d1, O[jj]);
        }
    }

    // ---------------- epilogue: out[c][n] = gamma*O/l + x ----------------
    __syncthreads();
    const float gam = gamma_p[0];
    f32x4 inv;
    #pragma unroll
    for (int q = 0; q < 4; ++q) inv[q] = gam / l_run[q];
    float* T = (float*)sm;                     // [512][68] f32 = 139264 B
    #pragma unroll
    for (int jj = 0; jj < 16; ++jj) {
        int crow = w1 * 256 + jj * 16 + l15;
        f32x4 v;
        #pragma unroll
        for (int q = 0; q < 4; ++q) v[q] = O[jj][q] * inv[q];
        *(f32x4*)(T + crow * 68 + wr * 16 + g * 4) = v;
    }
    __syncthreads();
    const float* __restrict__ xb = x + (size_t)b * CC * NN;
    float* __restrict__ ob = out + (size_t)b * CC * NN;
    #pragma unroll
    for (int it = 0; it < 16; ++it) {
        int c = (t >> 4) + it * 32;
        int n4 = (t & 15) * 4;
        f32x4 v = *(const f32x4*)(T + c * 68 + n4);
        f32x4 xv = *(const f32x4*)(xb + (size_t)c * NN + n0 + n4);
        #pragma unroll
        for (int q = 0; q < 4; ++q) v[q] += xv[q];
        *(f32x4*)(ob + (size_t)c * NN + n0 + n4) = v;
    }
}

extern "C" void kernel_launch(void* const* d_in, const int* in_sizes, int n_in,
                              void* d_out, int out_size, void* d_ws, size_t ws_size,
                              hipStream_t stream) {
    const float* x  = (const float*)d_in[0];
    const float* Wb = (const float*)d_in[1];
    const float* Wc = (const float*)d_in[2];
    const float* Wd = (const float*)d_in[3];
    const float* gm = (const float*)d_in[4];
    float* out = (float*)d_out;
    char* ws = (char*)d_ws;

    // ws: W16 1.5MB | Bt 16MB | Ct 16MB | Dm 16MB  (~49.5MB)
    f16* W16 = (f16*)(ws);
    f16* Bt  = (f16*)(ws + 1572864);
    f16* Ct  = (f16*)(ws + 1572864 + 16777216);
    f16* Dm  = (f16*)(ws + 1572864 + 2 * 16777216);

    wcvt_k<<<dim3(768), 256, 0, stream>>>(Wb, Wc, Wd, W16);
    proj_k<<<dim3(32, 4, 12), 256, 0, stream>>>(x, W16, Bt, Ct, Dm);
    flash_k<<<dim3(256), 512, 0, stream>>>(x, gm, Bt, Ct, Dm, out);
}